// Round 11
// baseline (179.120 us; speedup 1.0000x reference)
//
#include <hip/hip_runtime.h>
#include <hip/hip_bf16.h>
#include <math.h>

// MultiHeadAttentionQuantum, B=2048 S=1 E=1024 H=128 DK=NW=8
// All inputs/outputs float32.
//
// Algebra: S==1 -> attention out == v = x @ Wv^T (wq,wk dead).
// RX compose additively; CNOTs are XOR basis permutations ->
//   t_j = cos(v_j + rx_j);  qout[0]=t1*...*t7;  qout[w>=1]=t0*...*tw
// out = qout @ Wc^T + bc
//
// R10 post-mortem: f32-VGPR staging costs ~+11us vs async bf16 (R9/R10 both
// regressed) -> async global_load_lds staging is load-bearing; R8 (112.3us)
// stands. R11: merge both GEMMs into ONE cooperative kernel with per-m-row
// release/acquire counters (dependency of GEMM2 tile (m,n) is only the 16
// GEMM1 blocks of row m). No grid.sync (R6's 50us/sync trap). Removes the
// kernel gap + full-device drain; rows pipeline independently.

#define BB 2048
#define EN 1024

typedef short s16x8 __attribute__((ext_vector_type(8)));
typedef float f32x4 __attribute__((ext_vector_type(4)));

union Frag { s16x8 v; __hip_bfloat16 h[8]; };

__device__ inline s16x8 cvt_frag(f32x4 lo, f32x4 hi) {
    Frag u;
    #pragma unroll
    for (int j = 0; j < 4; ++j) {
        u.h[j]     = __float2bfloat16(lo[j]);
        u.h[4 + j] = __float2bfloat16(hi[j]);
    }
    return u.v;
}

// async 16B/lane global -> LDS (lds base wave-uniform; HW adds lane*16)
__device__ inline void gll16(const __hip_bfloat16* g, __hip_bfloat16* l) {
    __builtin_amdgcn_global_load_lds(
        (const __attribute__((address_space(1))) void*)g,
        (__attribute__((address_space(3))) void*)l,
        16, 0, 0);
}

// Convert x (262144 groups), wv, wc (131072 groups each) -> bf16; zero cnt.
__global__ __launch_bounds__(256) void cvt3_kernel(
        const float* __restrict__ x, const float* __restrict__ wv,
        const float* __restrict__ wc,
        __hip_bfloat16* __restrict__ xb, __hip_bfloat16* __restrict__ wvb,
        __hip_bfloat16* __restrict__ wcb, int* __restrict__ cnt)
{
    const int g = blockIdx.x * 256 + threadIdx.x;   // 0 .. 524287
    if (g < 32) cnt[g] = 0;
    const int NX = (BB * EN) / 8;                   // 262144
    const int NG = (EN * EN) / 8;                   // 131072
    const float* s; __hip_bfloat16* d; size_t off;
    if (g < NX)           { s = x;  d = xb;  off = (size_t)g * 8; }
    else if (g < NX + NG) { s = wv; d = wvb; off = (size_t)(g - NX) * 8; }
    else                  { s = wc; d = wcb; off = (size_t)(g - NX - NG) * 8; }
    f32x4 lo = *(const f32x4*)(s + off);
    f32x4 hi = *(const f32x4*)(s + off + 4);
    *(s16x8*)(d + off) = cvt_frag(lo, hi);
}

// One 64x64 tile of C[m,n] = sum_k A[m,k]*W[n,k]; A,W bf16 K-contiguous.
// 512 thr = 8 waves (4m x 2n), wave tile 16x32, BK=64 (16 iters),
// double-buffered frag-ordered LDS (32 KB): A tile (mt,kt) at (mt*2+kt)*512,
// B tile (nt,kt) at 4096+(nt*2+kt)*512; lane's mfma frag at tile + lane*8.
// EPI 0: quantum epilogue -> bf16 V.  EPI 1: +bias -> f32 out.
template <int EPI>
__device__ __forceinline__ void gemm_body(
        const __hip_bfloat16* __restrict__ A,
        const __hip_bfloat16* __restrict__ W,
        const float* __restrict__ bias, const float* __restrict__ rx,
        void* __restrict__ Cv, int m0, int n0, int tid,
        __hip_bfloat16* lds)
{
    const int wave = tid >> 6, lane = tid & 63;
    const int l15 = lane & 15, lq = lane >> 4;
    const int wmt = wave >> 1, wnt = wave & 1;

    const __hip_bfloat16* gsrc[2];
    int ldst[2];
    #pragma unroll
    for (int i = 0; i < 2; ++i) {
        const int t = wave * 2 + i;
        const __hip_bfloat16* base;
        int row, lofs;
        if (t < 8) { base = A; row = m0 + (t >> 1) * 16 + l15; lofs = t * 512; }
        else       { const int u = t - 8; base = W; row = n0 + (u >> 1) * 16 + l15; lofs = 4096 + u * 512; }
        gsrc[i] = base + (size_t)row * EN + (t & 1) * 32 + lq * 8;
        ldst[i] = lofs;          // wave-uniform; HW adds lane*16B
    }

    f32x4 acc[2] = {};

    #pragma unroll
    for (int i = 0; i < 2; ++i) gll16(gsrc[i], &lds[ldst[i]]);
    __syncthreads();

    int p = 0;
    for (int it = 1; it <= 16; ++it) {
        if (it < 16) {
            const int q = p ^ 1;
            #pragma unroll
            for (int i = 0; i < 2; ++i) gll16(gsrc[i] + it * 64, &lds[q * 8192 + ldst[i]]);
        }
        const __hip_bfloat16* Ab = &lds[p * 8192];
        const __hip_bfloat16* Bb = Ab + 4096;
        #pragma unroll
        for (int kt = 0; kt < 2; ++kt) {
            s16x8 a = *(const s16x8*)&Ab[(wmt * 2 + kt) * 512 + lane * 8];
            #pragma unroll
            for (int j = 0; j < 2; ++j) {
                s16x8 b = *(const s16x8*)&Bb[((wnt * 2 + j) * 2 + kt) * 512 + lane * 8];
                acc[j] = __builtin_amdgcn_mfma_f32_16x16x32_bf16(a, b, acc[j], 0, 0, 0);
            }
        }
        __syncthreads();   // drains vmcnt: next buffer staged; reads of p done
        p ^= 1;
    }

    if (EPI == 0) {
        // quantum epilogue: acc -> LDS f32 64x68 -> cos/products -> bf16 V
        float* sb = (float*)lds;
        #pragma unroll
        for (int j = 0; j < 2; ++j) {
            const int col = wnt * 32 + j * 16 + l15;
            #pragma unroll
            for (int r = 0; r < 4; ++r)
                sb[(wmt * 16 + lq * 4 + r) * 68 + col] = acc[j][r];
        }
        __syncthreads();
        const int row = tid >> 3, g = tid & 7;        // 64 rows x 8 groups
        const float* pv = &sb[row * 68 + g * 8];
        float t[8];
        #pragma unroll
        for (int j = 0; j < 8; ++j) t[j] = __cosf(pv[j] + rx[j]);
        Frag o;
        float suf = t[1];
        #pragma unroll
        for (int j = 2; j < 8; ++j) suf *= t[j];
        o.h[0] = __float2bfloat16(suf);
        float pr = t[0];
        #pragma unroll
        for (int j = 1; j < 8; ++j) { pr *= t[j]; o.h[j] = __float2bfloat16(pr); }
        __hip_bfloat16* V = (__hip_bfloat16*)Cv;
        *(s16x8*)(V + (size_t)(m0 + row) * EN + n0 + g * 8) = o.v;
    } else {
        float* C = (float*)Cv;
        #pragma unroll
        for (int j = 0; j < 2; ++j) {
            const int col = n0 + wnt * 32 + j * 16 + l15;
            const float bv = bias[col];
            #pragma unroll
            for (int r = 0; r < 4; ++r) {
                const int row = m0 + wmt * 16 + lq * 4 + r;
                C[(size_t)row * EN + col] = acc[j][r] + bv;
            }
        }
    }
}

// Cooperative fused kernel: 512 blocks x 512 thr (2 blocks/CU, co-resident).
// Block (mi = b>>4, ni = b&15): GEMM1 tile + quantum -> V; release cnt[mi];
// acquire-spin until cnt[mi]==16 (the 16 blocks of row mi); GEMM2 tile -> out.
__global__ __launch_bounds__(512, 4) void fused2_kernel(
        const __hip_bfloat16* __restrict__ xb,
        const __hip_bfloat16* __restrict__ wvb,
        const __hip_bfloat16* __restrict__ wcb,
        const float* __restrict__ bc, const float* __restrict__ rx,
        __hip_bfloat16* __restrict__ V, int* __restrict__ cnt,
        float* __restrict__ out)
{
    __shared__ __align__(16) __hip_bfloat16 lds[16384];   // 32 KB
    const int tid = threadIdx.x;
    const int mi = blockIdx.x >> 4, ni = blockIdx.x & 15;
    const int m0 = mi * 64, n0 = ni * 64;

    // phase 1: V tile = quantum(x @ Wv^T)
    gemm_body<0>(xb, wvb, nullptr, rx, V, m0, n0, tid, lds);
    __syncthreads();                       // all V stores of this block issued

    if (tid == 0) {
        __threadfence();                   // device-scope release of V stores
        __hip_atomic_fetch_add(&cnt[mi], 1, __ATOMIC_RELEASE,
                               __HIP_MEMORY_SCOPE_AGENT);
        while (__hip_atomic_load(&cnt[mi], __ATOMIC_ACQUIRE,
                                 __HIP_MEMORY_SCOPE_AGENT) < 16)
            __builtin_amdgcn_s_sleep(2);
    }
    __syncthreads();                       // row mi complete; caches acquired

    // phase 2: out tile = V @ Wc^T + bc
    gemm_body<1>(V, wcb, bc, nullptr, out, m0, n0, tid, lds);
}

extern "C" void kernel_launch(void* const* d_in, const int* in_sizes, int n_in,
                              void* d_out, int out_size, void* d_ws, size_t ws_size,
                              hipStream_t stream)
{
    // inputs: x, wq, wk, wv, wc, bc, rx_params (wq/wk dead: S==1)
    const float* x  = (const float*)d_in[0];
    const float* wv = (const float*)d_in[3];
    const float* wc = (const float*)d_in[4];
    const float* bc = (const float*)d_in[5];
    const float* rx = (const float*)d_in[6];
    float* out = (float*)d_out;

    const size_t XE = (size_t)BB * EN;   // 2M elems
    const size_t WE = (size_t)EN * EN;   // 1M elems

    // ws: [xb 4MB | wvb 2MB | wcb 2MB | V 4MB | cnt 128B]
    __hip_bfloat16* xb  = (__hip_bfloat16*)d_ws;
    __hip_bfloat16* wvb = xb + XE;
    __hip_bfloat16* wcb = wvb + WE;
    __hip_bfloat16* V   = wcb + WE;
    int* cnt = (int*)(V + XE);

    cvt3_kernel<<<(int)((XE / 8 + 2 * (WE / 8)) / 256), 256, 0, stream>>>(
        x, wv, wc, xb, wvb, wcb, cnt);

    void* args[] = { (void*)&xb, (void*)&wvb, (void*)&wcb, (void*)&bc,
                     (void*)&rx, (void*)&V, (void*)&cnt, (void*)&out };
    hipLaunchCooperativeKernel((const void*)fused2_kernel,
                               dim3(512), dim3(512), args, 0, stream);
}

// Round 13
// 140.184 us; speedup vs baseline: 1.2777x; 1.2777x over previous
//
#include <hip/hip_runtime.h>
#include <hip/hip_bf16.h>
#include <math.h>

// MultiHeadAttentionQuantum, B=2048 S=1 E=1024 H=128 DK=NW=8
// All inputs/outputs float32.
//
// Algebra: S==1 -> attention out == v = x @ Wv^T (wq,wk dead).
// RX compose additively; CNOTs are XOR basis permutations ->
//   t_j = cos(v_j + rx_j);  qout[0]=t1*...*t7;  qout[w>=1]=t0*...*tw
// out = qout @ Wc^T + bc
//
// R12 post-mortem: NaN — barrier-free loop had NOTHING waiting on the async
// global_load_lds DMA (no dest register -> backend inserts no vmcnt; the
// barrier in prior rounds was what drained it). R13 = R12 + explicit
// per-wave `s_waitcnt vmcnt(4)` after each prefetch issue (vmcnt(0) on the
// last iter) — the AITER-style "never drain to 0" wait, legal here because
// no barrier forces a full drain. Zero __syncthreads in the K-loop.

#define BB 2048
#define EN 1024

typedef short s16x8 __attribute__((ext_vector_type(8)));
typedef float f32x4 __attribute__((ext_vector_type(4)));

union Frag { s16x8 v; __hip_bfloat16 h[8]; };

__device__ inline s16x8 cvt_frag(f32x4 lo, f32x4 hi) {
    Frag u;
    #pragma unroll
    for (int j = 0; j < 4; ++j) {
        u.h[j]     = __float2bfloat16(lo[j]);
        u.h[4 + j] = __float2bfloat16(hi[j]);
    }
    return u.v;
}

// async 16B/lane global -> LDS (lds base wave-uniform; HW adds lane*16)
__device__ inline void gll16(const __hip_bfloat16* g, __hip_bfloat16* l) {
    __builtin_amdgcn_global_load_lds(
        (const __attribute__((address_space(1))) void*)g,
        (__attribute__((address_space(3))) void*)l,
        16, 0, 0);
}

// Convert x (262144 groups), wv, wc (131072 groups each) -> bf16.
__global__ __launch_bounds__(256) void cvt3_kernel(
        const float* __restrict__ x, const float* __restrict__ wv,
        const float* __restrict__ wc,
        __hip_bfloat16* __restrict__ xb, __hip_bfloat16* __restrict__ wvb,
        __hip_bfloat16* __restrict__ wcb)
{
    const int g = blockIdx.x * 256 + threadIdx.x;   // 0 .. 524287
    const int NX = (BB * EN) / 8;                   // 262144
    const int NG = (EN * EN) / 8;                   // 131072
    const float* s; __hip_bfloat16* d; size_t off;
    if (g < NX)           { s = x;  d = xb;  off = (size_t)g * 8; }
    else if (g < NX + NG) { s = wv; d = wvb; off = (size_t)(g - NX) * 8; }
    else                  { s = wc; d = wcb; off = (size_t)(g - NX - NG) * 8; }
    f32x4 lo = *(const f32x4*)(s + off);
    f32x4 hi = *(const f32x4*)(s + off + 4);
    *(s16x8*)(d + off) = cvt_frag(lo, hi);
}

// Barrier-free GEMM: C[m,n] = sum_k A[m,k]*W[n,k]; A,W bf16 K-contiguous.
// 256 thr = 4 waves (2m x 2n), wave tile 32x32 (2x2 16x16x32 mfma), BK=32.
// LDS: per-wave-private 4096 elems (2 buffers x [A0|A1|B0|B1] x 512);
// frag-ordered: lane l's mfma fragment at tile_base + l*8 elems (16B).
// DMA completion enforced by explicit per-wave s_waitcnt vmcnt(4)/(0).
// EPI 0: quantum epilogue (barriers only at end) -> bf16 V. EPI 1: +bias f32.
template <int EPI>
__global__ __launch_bounds__(256, 4) void gemm_kernel(
        const __hip_bfloat16* __restrict__ A,
        const __hip_bfloat16* __restrict__ W,
        const float* __restrict__ bias, const float* __restrict__ rx,
        void* __restrict__ Cv)
{
    __shared__ __align__(16) __hip_bfloat16 lds[16384];   // 32 KB

    const int tid  = threadIdx.x;
    const int wave = tid >> 6, lane = tid & 63;
    const int l15 = lane & 15, lq = lane >> 4;
    const int m0 = blockIdx.x * 64, n0 = blockIdx.y * 64;
    const int wm = (wave & 1) * 32, wn = (wave >> 1) * 32;

    __hip_bfloat16* wbase = &lds[wave * 4096];   // private: 2 bufs x 2048

    // tiles 0,1 = A (mt 0,1); 2,3 = B (nt 0,1); lane addr = row l15, k lq*8
    const __hip_bfloat16* gsrc[4];
    gsrc[0] = A + (size_t)(m0 + wm +      l15) * EN + lq * 8;
    gsrc[1] = A + (size_t)(m0 + wm + 16 + l15) * EN + lq * 8;
    gsrc[2] = W + (size_t)(n0 + wn +      l15) * EN + lq * 8;
    gsrc[3] = W + (size_t)(n0 + wn + 16 + l15) * EN + lq * 8;

    f32x4 acc[2][2] = {};

    #pragma unroll
    for (int i = 0; i < 4; ++i) gll16(gsrc[i], wbase + i * 512);

    int p = 0;
    for (int it = 1; it <= 32; ++it) {
        if (it < 32) {
            __hip_bfloat16* dst = wbase + (p ^ 1) * 2048;
            #pragma unroll
            for (int i = 0; i < 4; ++i) gll16(gsrc[i] + it * 32, dst + i * 512);
            // oldest 4 DMAs (current buffer) complete; newest 4 stay in flight
            asm volatile("s_waitcnt vmcnt(4)" ::: "memory");
        } else {
            // last buffer: drain all outstanding DMAs
            asm volatile("s_waitcnt vmcnt(0)" ::: "memory");
        }
        const __hip_bfloat16* buf = wbase + p * 2048;
        s16x8 a0 = *(const s16x8*)(buf +        lane * 8);
        s16x8 a1 = *(const s16x8*)(buf +  512 + lane * 8);
        s16x8 b0 = *(const s16x8*)(buf + 1024 + lane * 8);
        s16x8 b1 = *(const s16x8*)(buf + 1536 + lane * 8);
        acc[0][0] = __builtin_amdgcn_mfma_f32_16x16x32_bf16(a0, b0, acc[0][0], 0, 0, 0);
        acc[0][1] = __builtin_amdgcn_mfma_f32_16x16x32_bf16(a0, b1, acc[0][1], 0, 0, 0);
        acc[1][0] = __builtin_amdgcn_mfma_f32_16x16x32_bf16(a1, b0, acc[1][0], 0, 0, 0);
        acc[1][1] = __builtin_amdgcn_mfma_f32_16x16x32_bf16(a1, b1, acc[1][1], 0, 0, 0);
        p ^= 1;
    }

    if (EPI == 0) {
        // quantum epilogue: acc -> LDS f32 64x68 -> cos/products -> bf16 V
        __syncthreads();                 // waves done with private regions
        float* sb = (float*)lds;         // 64*68*4 = 17408 B
        #pragma unroll
        for (int mi = 0; mi < 2; ++mi)
            #pragma unroll
            for (int nj = 0; nj < 2; ++nj) {
                const int col = wn + nj * 16 + l15;
                #pragma unroll
                for (int r = 0; r < 4; ++r)
                    sb[(wm + mi * 16 + lq * 4 + r) * 68 + col] = acc[mi][nj][r];
            }
        __syncthreads();
        __hip_bfloat16* V = (__hip_bfloat16*)Cv;
        #pragma unroll
        for (int q = 0; q < 2; ++q) {
            const int idx = q * 256 + tid;        // 0..511 = 64 rows x 8 groups
            const int row = idx >> 3, g = idx & 7;
            const float* pv = &sb[row * 68 + g * 8];
            float t[8];
            #pragma unroll
            for (int j = 0; j < 8; ++j) t[j] = __cosf(pv[j] + rx[j]);
            Frag o;
            float suf = t[1];
            #pragma unroll
            for (int j = 2; j < 8; ++j) suf *= t[j];
            o.h[0] = __float2bfloat16(suf);
            float pr = t[0];
            #pragma unroll
            for (int j = 1; j < 8; ++j) { pr *= t[j]; o.h[j] = __float2bfloat16(pr); }
            *(s16x8*)(V + (size_t)(m0 + row) * EN + n0 + g * 8) = o.v;
        }
    } else {
        float* C = (float*)Cv;
        #pragma unroll
        for (int nj = 0; nj < 2; ++nj) {
            const int col = n0 + wn + nj * 16 + l15;
            const float bv = bias[col];
            #pragma unroll
            for (int mi = 0; mi < 2; ++mi)
                #pragma unroll
                for (int r = 0; r < 4; ++r) {
                    const int row = m0 + wm + mi * 16 + lq * 4 + r;
                    C[(size_t)row * EN + col] = acc[mi][nj][r] + bv;
                }
        }
    }
}

extern "C" void kernel_launch(void* const* d_in, const int* in_sizes, int n_in,
                              void* d_out, int out_size, void* d_ws, size_t ws_size,
                              hipStream_t stream)
{
    // inputs: x, wq, wk, wv, wc, bc, rx_params (wq/wk dead: S==1)
    const float* x  = (const float*)d_in[0];
    const float* wv = (const float*)d_in[3];
    const float* wc = (const float*)d_in[4];
    const float* bc = (const float*)d_in[5];
    const float* rx = (const float*)d_in[6];
    float* out = (float*)d_out;

    const size_t XE = (size_t)BB * EN;   // 2M elems
    const size_t WE = (size_t)EN * EN;   // 1M elems

    // ws (12 MB): [xb 4MB | wvb 2MB | wcb 2MB | V 4MB]
    __hip_bfloat16* xb  = (__hip_bfloat16*)d_ws;
    __hip_bfloat16* wvb = xb + XE;
    __hip_bfloat16* wcb = wvb + WE;
    __hip_bfloat16* V   = wcb + WE;

    dim3 grid(BB / 64, EN / 64);         // 32 x 16 = 512 blocks
    cvt3_kernel<<<(int)((XE / 8 + 2 * (WE / 8)) / 256), 256, 0, stream>>>(
        x, wv, wc, xb, wvb, wcb);
    gemm_kernel<0><<<grid, 256, 0, stream>>>(xb, wvb, nullptr, rx, V);
    gemm_kernel<1><<<grid, 256, 0, stream>>>(V, wcb, bc, nullptr, out);
}